// Round 17
// baseline (623.626 us; speedup 1.0000x reference)
//
#include <hip/hip_runtime.h>
#include <stdint.h>

// DIAGNOSTIC ROUND 2. Real pipeline = r13 (167.7us) byte-identical; THREE ablation
// dispatches appended (write scratch only, after combineF):
//   g1_noA    x6: gemm1 minus A-path (As zeroed; B GLD + MFMA + epilogue) -> base cost
//   g1_noStore x2: gemm1 minus Ab global stores -> store cost
//   g1_full2  x2: gemm1 verbatim to scratch -> in-situ anchor
// Decomposition tells which of {A-load chain, Ab stores, base loop} eats gemm1's 103us.
// ws: [0,128Mi) Ab | 128Mi Zt | 136Mi P | 256Mi Ab2(scratch) | 400Mi P2(scratch)

#define MK 8192

typedef float f32x4 __attribute__((ext_vector_type(4)));
typedef uint32_t u32x4 __attribute__((ext_vector_type(4)));
typedef uint32_t u32x2 __attribute__((ext_vector_type(2)));
typedef __bf16 bf16x8 __attribute__((ext_vector_type(8)));

__device__ inline uint16_t f2bf(float f) {
  uint32_t u = __builtin_bit_cast(uint32_t, f);
  u += 0x7fffu + ((u >> 16) & 1u);
  return (uint16_t)(u >> 16);
}
__device__ inline float bf2f(uint32_t lo16) {
  return __builtin_bit_cast(float, lo16 << 16);
}

#define GLD(src, dstbase)                                                                    \
  __builtin_amdgcn_global_load_lds((const __attribute__((address_space(1))) uint32_t*)(src), \
                                   (__attribute__((address_space(3))) uint32_t*)(dstbase),   \
                                   16, 0, 0)

// ---------------- zw0 ---------------------------------------------------------------------
__global__ __launch_bounds__(256) void zw0(const float* __restrict__ x,
                                           const float* __restrict__ net,
                                           uint16_t* __restrict__ Zt) {
  __shared__ float Wl[64 * 64];
  __shared__ float rows[64][65];
  const int b = blockIdx.y, n0 = blockIdx.x * 64, tid = threadIdx.x;
  for (int i = tid * 4; i < 4096; i += 1024) {
    f32x4 v = *(const f32x4*)(net + i);
    Wl[i] = v[0]; Wl[i + 1] = v[1]; Wl[i + 2] = v[2]; Wl[i + 3] = v[3];
  }
  const float* src = x + ((uint64_t)b * MK + n0) * 64;
  for (int i = tid * 4; i < 4096; i += 1024) {
    f32x4 v = *(const f32x4*)(src + i);
    int r = i >> 6, f = i & 63;
    rows[r][f] = v[0]; rows[r][f + 1] = v[1]; rows[r][f + 2] = v[2]; rows[r][f + 3] = v[3];
  }
  __syncthreads();
  const int nl = tid & 63, g0 = (tid >> 6) * 16;
  float s[16];
#pragma unroll
  for (int j = 0; j < 16; ++j) s[j] = 0.f;
  for (int f = 0; f < 64; ++f) {
    float rv = rows[nl][f];
#pragma unroll
    for (int j = 0; j < 16; ++j) s[j] = fmaf(rv, Wl[f * 64 + g0 + j], s[j]);
  }
  uint16_t* dst = Zt + (uint64_t)(b * 64 + g0) * MK + n0 + nl;
#pragma unroll
  for (int j = 0; j < 16; ++j) dst[(uint64_t)j * MK] = f2bf(s[j]);
}

// ---------------- gemm1 (r13 verbatim) ----------------------------------------------------
__global__ __launch_bounds__(512, 2) void gemm1(const float* __restrict__ Af,
                                                const uint16_t* __restrict__ Bt,
                                                uint16_t* __restrict__ Ab,
                                                uint16_t* __restrict__ P) {
  __shared__ __align__(16) uint16_t LB[65536];
#define AS1(b) (LB + (b)*16384)
#define BS1(b) (LB + 32768 + (b)*16384)
  const int bid = (int)blockIdx.x;
  const int s = bid & 7, bm = bid >> 3;
  const int row0 = bm * 256, k0 = s * 1024;
  const int tid = threadIdx.x, wid = tid >> 6, lane = tid & 63;
  const int wr = wid >> 2, wc = wid & 3;

  const int lsub = lane >> 3;
  const int ksrc = ((lane & 7) ^ lsub) << 3;
  const uint16_t* gB0 = Bt + (uint64_t)(4 * wid * 8 + lsub) * MK + k0 + ksrc;
  const int lBo = 4 * wid * 512;

  const int arow = (8 * wid) * 4 + (lane >> 4);
  const int acol = (lane & 15) * 4;
  const float* gA0 = Af + (uint64_t)(row0 + arow) * MK + k0 + acol;
  const int koct = (lane & 15) >> 1, krem = (lane & 1) * 4;

  f32x4 acc[8][4] = {};
  f32x4 rv[8];

  auto loadA = [&](int kofs) {
#pragma unroll
    for (int j = 0; j < 8; ++j)
      rv[j] = __builtin_nontemporal_load((const f32x4*)(gA0 + (uint64_t)j * 4 * MK + kofs));
  };
  auto stageA = [&](int buf, int kofs) {
#pragma unroll
    for (int j = 0; j < 8; ++j) {
      const int r = arow + j * 4;
      u32x2 w;
      w[0] = (uint32_t)f2bf(rv[j][0]) | ((uint32_t)f2bf(rv[j][1]) << 16);
      w[1] = (uint32_t)f2bf(rv[j][2]) | ((uint32_t)f2bf(rv[j][3]) << 16);
      *(u32x2*)&AS1(buf)[r * 64 + ((koct ^ (r & 7)) << 3) + krem] = w;
      *(u32x2*)(Ab + (uint64_t)(row0 + r) * MK + k0 + kofs + acol) = w;
    }
  };

  loadA(0);
#pragma unroll
  for (int j = 0; j < 4; ++j) GLD(gB0 + (uint64_t)j * 8 * MK, &BS1(0)[lBo + j * 512]);
  stageA(0, 0);
  __syncthreads();

  int buf = 0;
  for (int t = 0; t < 16; ++t) {
    const int nxt = (t + 1) * 64;
    if (t < 15) {
      loadA(nxt);
#pragma unroll
      for (int j = 0; j < 4; ++j) GLD(gB0 + (uint64_t)j * 8 * MK + nxt, &BS1(buf ^ 1)[lBo + j * 512]);
    }
#pragma unroll
    for (int kk = 0; kk < 2; ++kk) {
      const int kb = kk * 4 + (lane >> 4);
      bf16x8 a[8], b[4];
#pragma unroll
      for (int mi = 0; mi < 8; ++mi) {
        const int r = wr * 128 + mi * 16 + (lane & 15);
        a[mi] = *(const bf16x8*)&AS1(buf)[r * 64 + ((kb ^ (r & 7)) << 3)];
      }
#pragma unroll
      for (int n = 0; n < 4; ++n) {
        const int r = wc * 64 + n * 16 + (lane & 15);
        b[n] = *(const bf16x8*)&BS1(buf)[r * 64 + ((kb ^ (r & 7)) << 3)];
      }
#pragma unroll
      for (int mi = 0; mi < 8; ++mi)
#pragma unroll
        for (int n = 0; n < 4; ++n)
          acc[mi][n] = __builtin_amdgcn_mfma_f32_16x16x32_bf16(a[mi], b[n], acc[mi][n], 0, 0, 0);
    }
    if (t < 15) stageA(buf ^ 1, nxt);
    __syncthreads();
    buf ^= 1;
  }

  __syncthreads();
  const int lr = (lane >> 4) * 4, lc = lane & 15;
#pragma unroll
  for (int mi = 0; mi < 8; ++mi)
#pragma unroll
    for (int n = 0; n < 4; ++n)
#pragma unroll
      for (int j = 0; j < 4; ++j)
        LB[(wr * 128 + mi * 16 + lr + j) * 256 + (wc * 64 + n * 16 + lc)] = f2bf(acc[mi][n][j]);
  __syncthreads();
  uint16_t* Pp = P + (uint64_t)s * 2097152 + (uint64_t)row0 * 256;
#pragma unroll
  for (int i = 0; i < 16; ++i) {
    u32x4 v = *(const u32x4*)&LB[i * 4096 + tid * 8];
    *(u32x4*)(Pp + i * 4096 + tid * 8) = v;
  }
#undef AS1
#undef BS1
}

// ---------------- gemm2 (r13 verbatim) ----------------------------------------------------
__global__ __launch_bounds__(512, 2) void gemm2(const uint16_t* __restrict__ Ab,
                                                const uint16_t* __restrict__ Bt,
                                                uint16_t* __restrict__ P) {
  __shared__ __align__(16) uint16_t LB[65536];
#define AS2(b) (LB + (b)*16384)
#define BS2(b) (LB + 32768 + (b)*16384)
  const int bid = (int)blockIdx.x;
  const int s = bid & 7, bm = bid >> 3;
  const int row0 = bm * 256, k0 = s * 1024;
  const int tid = threadIdx.x, wid = tid >> 6, lane = tid & 63;
  const int wr = wid >> 2, wc = wid & 3;

  const int lsub = lane >> 3;
  const int ksrc = ((lane & 7) ^ lsub) << 3;
  const uint16_t* gA0 = Ab + (uint64_t)(row0 + 4 * wid * 8 + lsub) * MK + k0 + ksrc;
  const uint16_t* gB0 = Bt + (uint64_t)(4 * wid * 8 + lsub) * MK + k0 + ksrc;
  const int lo = 4 * wid * 512;

  f32x4 acc[8][4] = {};

#pragma unroll
  for (int j = 0; j < 4; ++j) {
    GLD(gA0 + (uint64_t)j * 8 * MK, &AS2(0)[lo + j * 512]);
    GLD(gB0 + (uint64_t)j * 8 * MK, &BS2(0)[lo + j * 512]);
  }

  int buf = 0;
  for (int t = 0; t < 16; ++t) {
    const int tko = ((t + 1) < 16 ? (t + 1) : 15) * 64;
#pragma unroll
    for (int j = 0; j < 4; ++j) {
      GLD(gA0 + (uint64_t)j * 8 * MK + tko, &AS2(buf ^ 1)[lo + j * 512]);
      GLD(gB0 + (uint64_t)j * 8 * MK + tko, &BS2(buf ^ 1)[lo + j * 512]);
    }
    asm volatile("s_waitcnt vmcnt(8)" ::: "memory");
    __builtin_amdgcn_s_barrier();
    __builtin_amdgcn_sched_barrier(0);

    bf16x8 b[4][2];
#pragma unroll
    for (int n = 0; n < 4; ++n)
#pragma unroll
      for (int kk = 0; kk < 2; ++kk) {
        const int r = wc * 64 + n * 16 + (lane & 15);
        const int kb = kk * 4 + (lane >> 4);
        b[n][kk] = *(const bf16x8*)&BS2(buf)[r * 64 + ((kb ^ (r & 7)) << 3)];
      }
#pragma unroll
    for (int q = 0; q < 4; ++q) {
      bf16x8 a[2][2];
#pragma unroll
      for (int i = 0; i < 2; ++i)
#pragma unroll
        for (int kk = 0; kk < 2; ++kk) {
          const int r = wr * 128 + (2 * q + i) * 16 + (lane & 15);
          const int kb = kk * 4 + (lane >> 4);
          a[i][kk] = *(const bf16x8*)&AS2(buf)[r * 64 + ((kb ^ (r & 7)) << 3)];
        }
      __builtin_amdgcn_s_setprio(1);
#pragma unroll
      for (int kk = 0; kk < 2; ++kk)
#pragma unroll
        for (int i = 0; i < 2; ++i)
#pragma unroll
          for (int n = 0; n < 4; ++n)
            acc[2 * q + i][n] =
                __builtin_amdgcn_mfma_f32_16x16x32_bf16(a[i][kk], b[n][kk], acc[2 * q + i][n], 0, 0, 0);
      __builtin_amdgcn_s_setprio(0);
      __builtin_amdgcn_sched_barrier(0);
    }
    __builtin_amdgcn_s_barrier();
    buf ^= 1;
  }

  __syncthreads();
  const int lr = (lane >> 4) * 4, lc = lane & 15;
#pragma unroll
  for (int mi = 0; mi < 8; ++mi)
#pragma unroll
    for (int n = 0; n < 4; ++n)
#pragma unroll
      for (int j = 0; j < 4; ++j)
        LB[(wr * 128 + mi * 16 + lr + j) * 256 + (wc * 64 + n * 16 + lc)] = f2bf(acc[mi][n][j]);
  __syncthreads();
  uint16_t* Pp = P + (uint64_t)s * 2097152 + (uint64_t)row0 * 256;
#pragma unroll
  for (int i = 0; i < 16; ++i) {
    u32x4 v = *(const u32x4*)&LB[i * 4096 + tid * 8];
    *(u32x4*)(Pp + i * 4096 + tid * 8) = v;
  }
#undef AS2
#undef BS2
}

// ---------------- zw1P --------------------------------------------------------------------
__global__ __launch_bounds__(256) void zw1P(const uint16_t* __restrict__ P,
                                            const float* __restrict__ net,
                                            uint16_t* __restrict__ Zt) {
  __shared__ float Wl[64 * 64];
  __shared__ float rows[64][65];
  const int b = blockIdx.y, n0 = blockIdx.x * 64, tid = threadIdx.x;
  const float* Wsrc = net + 4096;
  for (int i = tid * 4; i < 4096; i += 1024) {
    f32x4 v = *(const f32x4*)(Wsrc + i);
    Wl[i] = v[0]; Wl[i + 1] = v[1]; Wl[i + 2] = v[2]; Wl[i + 3] = v[3];
  }
#pragma unroll
  for (int g = 0; g < 2; ++g) {
    const int idx = (tid + g * 256) * 8;
    const int r = idx >> 6, f0 = idx & 63;
    const uint16_t* base = P + (uint64_t)(n0 + r) * 256 + b * 64 + f0;
    float acc8[8] = {};
#pragma unroll
    for (int sp = 0; sp < 8; ++sp) {
      u32x4 v = *(const u32x4*)(base + (uint64_t)sp * 2097152);
#pragma unroll
      for (int j = 0; j < 4; ++j) {
        acc8[2 * j]     += bf2f(v[j] & 0xffffu);
        acc8[2 * j + 1] += bf2f(v[j] >> 16);
      }
    }
#pragma unroll
    for (int j = 0; j < 8; ++j) rows[r][f0 + j] = fmaxf(acc8[j], 0.0f);
  }
  __syncthreads();
  const int nl = tid & 63, g0 = (tid >> 6) * 16;
  float s[16];
#pragma unroll
  for (int j = 0; j < 16; ++j) s[j] = 0.f;
  for (int f = 0; f < 64; ++f) {
    float rv = rows[nl][f];
#pragma unroll
    for (int j = 0; j < 16; ++j) s[j] = fmaf(rv, Wl[f * 64 + g0 + j], s[j]);
  }
  uint16_t* dst = Zt + (uint64_t)(b * 64 + g0) * MK + n0 + nl;
#pragma unroll
  for (int j = 0; j < 16; ++j) dst[(uint64_t)j * MK] = f2bf(s[j]);
}

// ---------------- combineF ----------------------------------------------------------------
__global__ __launch_bounds__(256) void combineF(const uint16_t* __restrict__ P,
                                                float* __restrict__ out) {
  const uint64_t e = ((uint64_t)blockIdx.x * 256 + threadIdx.x) * 8;
  float acc8[8] = {};
#pragma unroll
  for (int sp = 0; sp < 8; ++sp) {
    u32x4 v = *(const u32x4*)&P[(uint64_t)sp * 2097152 + e];
#pragma unroll
    for (int j = 0; j < 4; ++j) {
      acc8[2 * j]     += bf2f(v[j] & 0xffffu);
      acc8[2 * j + 1] += bf2f(v[j] >> 16);
    }
  }
  const int m = (int)(e >> 8);
  const int c = (int)(e & 255);
  float* dst = &out[(((uint64_t)(c >> 6)) * MK + m) * 64 + (c & 63)];
  f32x4 w0, w1;
#pragma unroll
  for (int j = 0; j < 4; ++j) { w0[j] = fmaxf(acc8[j], 0.0f); w1[j] = fmaxf(acc8[4 + j], 0.0f); }
  *(f32x4*)dst = w0;
  *(f32x4*)(dst + 4) = w1;
}

// ================= DIAGNOSTICS (scratch-only; run after real pipeline) ====================

// g1_noA: gemm1 minus A-path. As zeroed; B GLD + MFMA + epilogue. REPS inner.
__global__ __launch_bounds__(512, 2) void g1_noA(const uint16_t* __restrict__ Bt,
                                                 uint16_t* __restrict__ P2) {
  __shared__ __align__(16) uint16_t LB[65536];
#define ASD(b) (LB + (b)*16384)
#define BSD(b) (LB + 32768 + (b)*16384)
  const int bid = (int)blockIdx.x;
  const int s = bid & 7, bm = bid >> 3;
  const int row0 = bm * 256, k0 = s * 1024;
  const int tid = threadIdx.x, wid = tid >> 6, lane = tid & 63;
  const int wr = wid >> 2, wc = wid & 3;
  const int lsub = lane >> 3;
  const int ksrc = ((lane & 7) ^ lsub) << 3;
  const uint16_t* gB0 = Bt + (uint64_t)(4 * wid * 8 + lsub) * MK + k0 + ksrc;
  const int lBo = 4 * wid * 512;

  for (int i = tid * 8; i < 32768; i += 4096) *(u32x4*)&LB[i] = u32x4{0, 0, 0, 0};
  __syncthreads();

  f32x4 acc[8][4];
  for (int rep = 0; rep < 6; ++rep) {
#pragma unroll
    for (int mi = 0; mi < 8; ++mi)
#pragma unroll
      for (int n = 0; n < 4; ++n) acc[mi][n] = f32x4{0.f, 0.f, 0.f, 0.f};
#pragma unroll
    for (int j = 0; j < 4; ++j) GLD(gB0 + (uint64_t)j * 8 * MK, &BSD(0)[lBo + j * 512]);
    __syncthreads();
    int buf = 0;
    for (int t = 0; t < 16; ++t) {
      if (t < 15) {
        const int nxt = (t + 1) * 64;
#pragma unroll
        for (int j = 0; j < 4; ++j) GLD(gB0 + (uint64_t)j * 8 * MK + nxt, &BSD(buf ^ 1)[lBo + j * 512]);
      }
#pragma unroll
      for (int kk = 0; kk < 2; ++kk) {
        const int kb = kk * 4 + (lane >> 4);
        bf16x8 a[8], b[4];
#pragma unroll
        for (int mi = 0; mi < 8; ++mi) {
          const int r = wr * 128 + mi * 16 + (lane & 15);
          a[mi] = *(const bf16x8*)&ASD(buf)[r * 64 + ((kb ^ (r & 7)) << 3)];
        }
#pragma unroll
        for (int n = 0; n < 4; ++n) {
          const int r = wc * 64 + n * 16 + (lane & 15);
          b[n] = *(const bf16x8*)&BSD(buf)[r * 64 + ((kb ^ (r & 7)) << 3)];
        }
#pragma unroll
        for (int mi = 0; mi < 8; ++mi)
#pragma unroll
          for (int n = 0; n < 4; ++n)
            acc[mi][n] = __builtin_amdgcn_mfma_f32_16x16x32_bf16(a[mi], b[n], acc[mi][n], 0, 0, 0);
      }
      __syncthreads();
      buf ^= 1;
    }
  }
  __syncthreads();
  const int lr = (lane >> 4) * 4, lc = lane & 15;
#pragma unroll
  for (int mi = 0; mi < 8; ++mi)
#pragma unroll
    for (int n = 0; n < 4; ++n)
#pragma unroll
      for (int j = 0; j < 4; ++j)
        LB[(wr * 128 + mi * 16 + lr + j) * 256 + (wc * 64 + n * 16 + lc)] = f2bf(acc[mi][n][j]);
  __syncthreads();
  uint16_t* Pp = P2 + (uint64_t)s * 2097152 + (uint64_t)row0 * 256;
#pragma unroll
  for (int i = 0; i < 16; ++i) {
    u32x4 v = *(const u32x4*)&LB[i * 4096 + tid * 8];
    *(u32x4*)(Pp + i * 4096 + tid * 8) = v;
  }
#undef ASD
#undef BSD
}

// g1_ns: gemm1 minus Ab stores (NS=1) or verbatim (NS=0). REPS inner.
template <int NS, int REPS>
__global__ __launch_bounds__(512, 2) void g1_ns(const float* __restrict__ Af,
                                                const uint16_t* __restrict__ Bt,
                                                uint16_t* __restrict__ Ab2,
                                                uint16_t* __restrict__ P2) {
  __shared__ __align__(16) uint16_t LB[65536];
#define ASD(b) (LB + (b)*16384)
#define BSD(b) (LB + 32768 + (b)*16384)
  const int bid = (int)blockIdx.x;
  const int s = bid & 7, bm = bid >> 3;
  const int row0 = bm * 256, k0 = s * 1024;
  const int tid = threadIdx.x, wid = tid >> 6, lane = tid & 63;
  const int wr = wid >> 2, wc = wid & 3;
  const int lsub = lane >> 3;
  const int ksrc = ((lane & 7) ^ lsub) << 3;
  const uint16_t* gB0 = Bt + (uint64_t)(4 * wid * 8 + lsub) * MK + k0 + ksrc;
  const int lBo = 4 * wid * 512;
  const int arow = (8 * wid) * 4 + (lane >> 4);
  const int acol = (lane & 15) * 4;
  const float* gA0 = Af + (uint64_t)(row0 + arow) * MK + k0 + acol;
  const int koct = (lane & 15) >> 1, krem = (lane & 1) * 4;

  f32x4 acc[8][4];
  f32x4 rv[8];

  auto loadA = [&](int kofs) {
#pragma unroll
    for (int j = 0; j < 8; ++j)
      rv[j] = __builtin_nontemporal_load((const f32x4*)(gA0 + (uint64_t)j * 4 * MK + kofs));
  };
  auto stageA = [&](int buf, int kofs) {
#pragma unroll
    for (int j = 0; j < 8; ++j) {
      const int r = arow + j * 4;
      u32x2 w;
      w[0] = (uint32_t)f2bf(rv[j][0]) | ((uint32_t)f2bf(rv[j][1]) << 16);
      w[1] = (uint32_t)f2bf(rv[j][2]) | ((uint32_t)f2bf(rv[j][3]) << 16);
      *(u32x2*)&ASD(buf)[r * 64 + ((koct ^ (r & 7)) << 3) + krem] = w;
      if (NS == 0) *(u32x2*)(Ab2 + (uint64_t)(row0 + r) * MK + k0 + kofs + acol) = w;
    }
  };

  for (int rep = 0; rep < REPS; ++rep) {
#pragma unroll
    for (int mi = 0; mi < 8; ++mi)
#pragma unroll
      for (int n = 0; n < 4; ++n) acc[mi][n] = f32x4{0.f, 0.f, 0.f, 0.f};
    loadA(0);
#pragma unroll
    for (int j = 0; j < 4; ++j) GLD(gB0 + (uint64_t)j * 8 * MK, &BSD(0)[lBo + j * 512]);
    stageA(0, 0);
    __syncthreads();
    int buf = 0;
    for (int t = 0; t < 16; ++t) {
      const int nxt = (t + 1) * 64;
      if (t < 15) {
        loadA(nxt);
#pragma unroll
        for (int j = 0; j < 4; ++j) GLD(gB0 + (uint64_t)j * 8 * MK + nxt, &BSD(buf ^ 1)[lBo + j * 512]);
      }
#pragma unroll
      for (int kk = 0; kk < 2; ++kk) {
        const int kb = kk * 4 + (lane >> 4);
        bf16x8 a[8], b[4];
#pragma unroll
        for (int mi = 0; mi < 8; ++mi) {
          const int r = wr * 128 + mi * 16 + (lane & 15);
          a[mi] = *(const bf16x8*)&ASD(buf)[r * 64 + ((kb ^ (r & 7)) << 3)];
        }
#pragma unroll
        for (int n = 0; n < 4; ++n) {
          const int r = wc * 64 + n * 16 + (lane & 15);
          b[n] = *(const bf16x8*)&BSD(buf)[r * 64 + ((kb ^ (r & 7)) << 3)];
        }
#pragma unroll
        for (int mi = 0; mi < 8; ++mi)
#pragma unroll
          for (int n = 0; n < 4; ++n)
            acc[mi][n] = __builtin_amdgcn_mfma_f32_16x16x32_bf16(a[mi], b[n], acc[mi][n], 0, 0, 0);
      }
      if (t < 15) stageA(buf ^ 1, nxt);
      __syncthreads();
      buf ^= 1;
    }
  }
  __syncthreads();
  const int lr = (lane >> 4) * 4, lc = lane & 15;
#pragma unroll
  for (int mi = 0; mi < 8; ++mi)
#pragma unroll
    for (int n = 0; n < 4; ++n)
#pragma unroll
      for (int j = 0; j < 4; ++j)
        LB[(wr * 128 + mi * 16 + lr + j) * 256 + (wc * 64 + n * 16 + lc)] = f2bf(acc[mi][n][j]);
  __syncthreads();
  uint16_t* Pp = P2 + (uint64_t)s * 2097152 + (uint64_t)row0 * 256;
#pragma unroll
  for (int i = 0; i < 16; ++i) {
    u32x4 v = *(const u32x4*)&LB[i * 4096 + tid * 8];
    *(u32x4*)(Pp + i * 4096 + tid * 8) = v;
  }
#undef ASD
#undef BSD
}

extern "C" void kernel_launch(void* const* d_in, const int* in_sizes, int n_in,
                              void* d_out, int out_size, void* d_ws, size_t ws_size,
                              hipStream_t stream) {
  const float* x   = (const float*)d_in[0];
  const float* net = (const float*)d_in[2];
  const float* A   = (const float*)d_in[3];
  float* out = (float*)d_out;

  uint16_t* Ab  = (uint16_t*)d_ws;
  uint16_t* Zt  = (uint16_t*)((char*)d_ws + 134217728ull);
  uint16_t* P   = (uint16_t*)((char*)d_ws + 142606336ull);
  uint16_t* Ab2 = (uint16_t*)((char*)d_ws + 268435456ull);   // scratch
  uint16_t* P2  = (uint16_t*)((char*)d_ws + 419430400ull);   // scratch

  zw0<<<dim3(128, 4), dim3(256), 0, stream>>>(x, net, Zt);
  gemm1<<<dim3(256), dim3(512), 0, stream>>>(A, Zt, Ab, P);
  zw1P<<<dim3(128, 4), dim3(256), 0, stream>>>(P, net, Zt);
  gemm2<<<dim3(256), dim3(512), 0, stream>>>(Ab, Zt, P);
  combineF<<<dim3(1024), dim3(256), 0, stream>>>(P, out);

  // diagnostics (scratch only)
  g1_noA<<<dim3(256), dim3(512), 0, stream>>>(Zt, P2);
  g1_ns<1, 2><<<dim3(256), dim3(512), 0, stream>>>(A, Zt, Ab2, P2);
  g1_ns<0, 2><<<dim3(256), dim3(512), 0, stream>>>(A, Zt, Ab2, P2);
}

// Round 18
// 167.292 us; speedup vs baseline: 3.7278x; 3.7278x over previous
//
#include <hip/hip_runtime.h>
#include <stdint.h>

// B=4, N=8192, F=64, L=2:  z = x; 2x: z = relu(A @ z @ W_l)  ==  relu(A @ (z @ W_l))
// Base = r13 (167.7us). ONE mechanism: VGPR cap. r17 decomposition: gemm1's A register
// path (loadA->rv->stageA) = ~90 of 99us; Ab stores ~0; base loop 9.5us. Cause:
// __launch_bounds__(512,2) caps VGPR at 128 (counter-confirmed) but kernel needs ~220
// (acc 128 + rv 32 + frags 48 + addr) -> rv spills to scratch (L2-resident, invisible
// in HBM counters, ~200cy/access) every tile. Fix: launch_bounds (512,1) -> 256 VGPR
// cap on both gemms. LDS 128KiB already limits to 1 block/CU => zero occupancy cost.
// Pipeline: zw0 -> gemm1(fused cvt) -> zw1P -> gemm2 -> combineF   (r13-identical)
// ws: [0,128Mi) Ab | [128Mi,+4Mi) Zt | [136Mi,+32Mi) P (bf16 [8][8192][256])

#define MK 8192

typedef float f32x4 __attribute__((ext_vector_type(4)));
typedef uint32_t u32x4 __attribute__((ext_vector_type(4)));
typedef uint32_t u32x2 __attribute__((ext_vector_type(2)));
typedef __bf16 bf16x8 __attribute__((ext_vector_type(8)));

__device__ inline uint16_t f2bf(float f) {
  uint32_t u = __builtin_bit_cast(uint32_t, f);
  u += 0x7fffu + ((u >> 16) & 1u);   // RNE (finite randn inputs)
  return (uint16_t)(u >> 16);
}
__device__ inline float bf2f(uint32_t lo16) {
  return __builtin_bit_cast(float, lo16 << 16);
}

#define GLD(src, dstbase)                                                                    \
  __builtin_amdgcn_global_load_lds((const __attribute__((address_space(1))) uint32_t*)(src), \
                                   (__attribute__((address_space(3))) uint32_t*)(dstbase),   \
                                   16, 0, 0)

// ---------------- zw0: Zt = (x @ W0)^T ----------------------------------------------------
__global__ __launch_bounds__(256) void zw0(const float* __restrict__ x,
                                           const float* __restrict__ net,
                                           uint16_t* __restrict__ Zt) {
  __shared__ float Wl[64 * 64];
  __shared__ float rows[64][65];
  const int b = blockIdx.y, n0 = blockIdx.x * 64, tid = threadIdx.x;
  for (int i = tid * 4; i < 4096; i += 1024) {
    f32x4 v = *(const f32x4*)(net + i);
    Wl[i] = v[0]; Wl[i + 1] = v[1]; Wl[i + 2] = v[2]; Wl[i + 3] = v[3];
  }
  const float* src = x + ((uint64_t)b * MK + n0) * 64;
  for (int i = tid * 4; i < 4096; i += 1024) {
    f32x4 v = *(const f32x4*)(src + i);
    int r = i >> 6, f = i & 63;
    rows[r][f] = v[0]; rows[r][f + 1] = v[1]; rows[r][f + 2] = v[2]; rows[r][f + 3] = v[3];
  }
  __syncthreads();
  const int nl = tid & 63, g0 = (tid >> 6) * 16;
  float s[16];
#pragma unroll
  for (int j = 0; j < 16; ++j) s[j] = 0.f;
  for (int f = 0; f < 64; ++f) {
    float rv = rows[nl][f];
#pragma unroll
    for (int j = 0; j < 16; ++j) s[j] = fmaf(rv, Wl[f * 64 + g0 + j], s[j]);
  }
  uint16_t* dst = Zt + (uint64_t)(b * 64 + g0) * MK + n0 + nl;
#pragma unroll
  for (int j = 0; j < 16; ++j) dst[(uint64_t)j * MK] = f2bf(s[j]);
}

// ---------------- gemm1: r13 loop, VGPR cap 256 (launch_bounds 512,1) ---------------------
__global__ __launch_bounds__(512, 1) void gemm1(const float* __restrict__ Af,
                                                const uint16_t* __restrict__ Bt,
                                                uint16_t* __restrict__ Ab,
                                                uint16_t* __restrict__ P) {
  __shared__ __align__(16) uint16_t LB[65536];
#define AS1(b) (LB + (b)*16384)
#define BS1(b) (LB + 32768 + (b)*16384)
  const int bid = (int)blockIdx.x;
  const int s = bid & 7, bm = bid >> 3;
  const int row0 = bm * 256, k0 = s * 1024;
  const int tid = threadIdx.x, wid = tid >> 6, lane = tid & 63;
  const int wr = wid >> 2, wc = wid & 3;

  const int lsub = lane >> 3;
  const int ksrc = ((lane & 7) ^ lsub) << 3;
  const uint16_t* gB0 = Bt + (uint64_t)(4 * wid * 8 + lsub) * MK + k0 + ksrc;
  const int lBo = 4 * wid * 512;

  const int arow = (8 * wid) * 4 + (lane >> 4);
  const int acol = (lane & 15) * 4;
  const float* gA0 = Af + (uint64_t)(row0 + arow) * MK + k0 + acol;
  const int koct = (lane & 15) >> 1, krem = (lane & 1) * 4;

  f32x4 acc[8][4] = {};
  f32x4 rv[8];

  auto loadA = [&](int kofs) {
#pragma unroll
    for (int j = 0; j < 8; ++j)
      rv[j] = __builtin_nontemporal_load((const f32x4*)(gA0 + (uint64_t)j * 4 * MK + kofs));
  };
  auto stageA = [&](int buf, int kofs) {
#pragma unroll
    for (int j = 0; j < 8; ++j) {
      const int r = arow + j * 4;
      u32x2 w;
      w[0] = (uint32_t)f2bf(rv[j][0]) | ((uint32_t)f2bf(rv[j][1]) << 16);
      w[1] = (uint32_t)f2bf(rv[j][2]) | ((uint32_t)f2bf(rv[j][3]) << 16);
      *(u32x2*)&AS1(buf)[r * 64 + ((koct ^ (r & 7)) << 3) + krem] = w;
      *(u32x2*)(Ab + (uint64_t)(row0 + r) * MK + k0 + kofs + acol) = w;
    }
  };

  loadA(0);
#pragma unroll
  for (int j = 0; j < 4; ++j) GLD(gB0 + (uint64_t)j * 8 * MK, &BS1(0)[lBo + j * 512]);
  stageA(0, 0);
  __syncthreads();

  int buf = 0;
  for (int t = 0; t < 16; ++t) {
    const int nxt = (t + 1) * 64;
    if (t < 15) {
      loadA(nxt);
#pragma unroll
      for (int j = 0; j < 4; ++j) GLD(gB0 + (uint64_t)j * 8 * MK + nxt, &BS1(buf ^ 1)[lBo + j * 512]);
    }
#pragma unroll
    for (int kk = 0; kk < 2; ++kk) {
      const int kb = kk * 4 + (lane >> 4);
      bf16x8 a[8], b[4];
#pragma unroll
      for (int mi = 0; mi < 8; ++mi) {
        const int r = wr * 128 + mi * 16 + (lane & 15);
        a[mi] = *(const bf16x8*)&AS1(buf)[r * 64 + ((kb ^ (r & 7)) << 3)];
      }
#pragma unroll
      for (int n = 0; n < 4; ++n) {
        const int r = wc * 64 + n * 16 + (lane & 15);
        b[n] = *(const bf16x8*)&BS1(buf)[r * 64 + ((kb ^ (r & 7)) << 3)];
      }
#pragma unroll
      for (int mi = 0; mi < 8; ++mi)
#pragma unroll
        for (int n = 0; n < 4; ++n)
          acc[mi][n] = __builtin_amdgcn_mfma_f32_16x16x32_bf16(a[mi], b[n], acc[mi][n], 0, 0, 0);
    }
    if (t < 15) stageA(buf ^ 1, nxt);
    __syncthreads();
    buf ^= 1;
  }

  __syncthreads();
  const int lr = (lane >> 4) * 4, lc = lane & 15;
#pragma unroll
  for (int mi = 0; mi < 8; ++mi)
#pragma unroll
    for (int n = 0; n < 4; ++n)
#pragma unroll
      for (int j = 0; j < 4; ++j)
        LB[(wr * 128 + mi * 16 + lr + j) * 256 + (wc * 64 + n * 16 + lc)] = f2bf(acc[mi][n][j]);
  __syncthreads();
  uint16_t* Pp = P + (uint64_t)s * 2097152 + (uint64_t)row0 * 256;
#pragma unroll
  for (int i = 0; i < 16; ++i) {
    u32x4 v = *(const u32x4*)&LB[i * 4096 + tid * 8];
    *(u32x4*)(Pp + i * 4096 + tid * 8) = v;
  }
#undef AS1
#undef BS1
}

// ---------------- gemm2: r13 loop, VGPR cap 256 -------------------------------------------
__global__ __launch_bounds__(512, 1) void gemm2(const uint16_t* __restrict__ Ab,
                                                const uint16_t* __restrict__ Bt,
                                                uint16_t* __restrict__ P) {
  __shared__ __align__(16) uint16_t LB[65536];
#define AS2(b) (LB + (b)*16384)
#define BS2(b) (LB + 32768 + (b)*16384)
  const int bid = (int)blockIdx.x;
  const int s = bid & 7, bm = bid >> 3;
  const int row0 = bm * 256, k0 = s * 1024;
  const int tid = threadIdx.x, wid = tid >> 6, lane = tid & 63;
  const int wr = wid >> 2, wc = wid & 3;

  const int lsub = lane >> 3;
  const int ksrc = ((lane & 7) ^ lsub) << 3;
  const uint16_t* gA0 = Ab + (uint64_t)(row0 + 4 * wid * 8 + lsub) * MK + k0 + ksrc;
  const uint16_t* gB0 = Bt + (uint64_t)(4 * wid * 8 + lsub) * MK + k0 + ksrc;
  const int lo = 4 * wid * 512;

  f32x4 acc[8][4] = {};

#pragma unroll
  for (int j = 0; j < 4; ++j) {
    GLD(gA0 + (uint64_t)j * 8 * MK, &AS2(0)[lo + j * 512]);
    GLD(gB0 + (uint64_t)j * 8 * MK, &BS2(0)[lo + j * 512]);
  }

  int buf = 0;
  for (int t = 0; t < 16; ++t) {
    const int tko = ((t + 1) < 16 ? (t + 1) : 15) * 64;
#pragma unroll
    for (int j = 0; j < 4; ++j) {
      GLD(gA0 + (uint64_t)j * 8 * MK + tko, &AS2(buf ^ 1)[lo + j * 512]);
      GLD(gB0 + (uint64_t)j * 8 * MK + tko, &BS2(buf ^ 1)[lo + j * 512]);
    }
    asm volatile("s_waitcnt vmcnt(8)" ::: "memory");
    __builtin_amdgcn_s_barrier();
    __builtin_amdgcn_sched_barrier(0);

    bf16x8 b[4][2];
#pragma unroll
    for (int n = 0; n < 4; ++n)
#pragma unroll
      for (int kk = 0; kk < 2; ++kk) {
        const int r = wc * 64 + n * 16 + (lane & 15);
        const int kb = kk * 4 + (lane >> 4);
        b[n][kk] = *(const bf16x8*)&BS2(buf)[r * 64 + ((kb ^ (r & 7)) << 3)];
      }
#pragma unroll
    for (int q = 0; q < 4; ++q) {
      bf16x8 a[2][2];
#pragma unroll
      for (int i = 0; i < 2; ++i)
#pragma unroll
        for (int kk = 0; kk < 2; ++kk) {
          const int r = wr * 128 + (2 * q + i) * 16 + (lane & 15);
          const int kb = kk * 4 + (lane >> 4);
          a[i][kk] = *(const bf16x8*)&AS2(buf)[r * 64 + ((kb ^ (r & 7)) << 3)];
        }
      __builtin_amdgcn_s_setprio(1);
#pragma unroll
      for (int kk = 0; kk < 2; ++kk)
#pragma unroll
        for (int i = 0; i < 2; ++i)
#pragma unroll
          for (int n = 0; n < 4; ++n)
            acc[2 * q + i][n] =
                __builtin_amdgcn_mfma_f32_16x16x32_bf16(a[i][kk], b[n][kk], acc[2 * q + i][n], 0, 0, 0);
      __builtin_amdgcn_s_setprio(0);
      __builtin_amdgcn_sched_barrier(0);
    }
    __builtin_amdgcn_s_barrier();
    buf ^= 1;
  }

  __syncthreads();
  const int lr = (lane >> 4) * 4, lc = lane & 15;
#pragma unroll
  for (int mi = 0; mi < 8; ++mi)
#pragma unroll
    for (int n = 0; n < 4; ++n)
#pragma unroll
      for (int j = 0; j < 4; ++j)
        LB[(wr * 128 + mi * 16 + lr + j) * 256 + (wc * 64 + n * 16 + lc)] = f2bf(acc[mi][n][j]);
  __syncthreads();
  uint16_t* Pp = P + (uint64_t)s * 2097152 + (uint64_t)row0 * 256;
#pragma unroll
  for (int i = 0; i < 16; ++i) {
    u32x4 v = *(const u32x4*)&LB[i * 4096 + tid * 8];
    *(u32x4*)(Pp + i * 4096 + tid * 8) = v;
  }
#undef AS2
#undef BS2
}

// ---------------- zw1P: rows = relu(sum_s P[s] (bf16)); Zt = rows @ W1 --------------------
__global__ __launch_bounds__(256) void zw1P(const uint16_t* __restrict__ P,
                                            const float* __restrict__ net,
                                            uint16_t* __restrict__ Zt) {
  __shared__ float Wl[64 * 64];
  __shared__ float rows[64][65];
  const int b = blockIdx.y, n0 = blockIdx.x * 64, tid = threadIdx.x;
  const float* Wsrc = net + 4096;
  for (int i = tid * 4; i < 4096; i += 1024) {
    f32x4 v = *(const f32x4*)(Wsrc + i);
    Wl[i] = v[0]; Wl[i + 1] = v[1]; Wl[i + 2] = v[2]; Wl[i + 3] = v[3];
  }
#pragma unroll
  for (int g = 0; g < 2; ++g) {
    const int idx = (tid + g * 256) * 8;
    const int r = idx >> 6, f0 = idx & 63;
    const uint16_t* base = P + (uint64_t)(n0 + r) * 256 + b * 64 + f0;
    float acc8[8] = {};
#pragma unroll
    for (int sp = 0; sp < 8; ++sp) {
      u32x4 v = *(const u32x4*)(base + (uint64_t)sp * 2097152);
#pragma unroll
      for (int j = 0; j < 4; ++j) {
        acc8[2 * j]     += bf2f(v[j] & 0xffffu);
        acc8[2 * j + 1] += bf2f(v[j] >> 16);
      }
    }
#pragma unroll
    for (int j = 0; j < 8; ++j) rows[r][f0 + j] = fmaxf(acc8[j], 0.0f);
  }
  __syncthreads();
  const int nl = tid & 63, g0 = (tid >> 6) * 16;
  float s[16];
#pragma unroll
  for (int j = 0; j < 16; ++j) s[j] = 0.f;
  for (int f = 0; f < 64; ++f) {
    float rv = rows[nl][f];
#pragma unroll
    for (int j = 0; j < 16; ++j) s[j] = fmaf(rv, Wl[f * 64 + g0 + j], s[j]);
  }
  uint16_t* dst = Zt + (uint64_t)(b * 64 + g0) * MK + n0 + nl;
#pragma unroll
  for (int j = 0; j < 16; ++j) dst[(uint64_t)j * MK] = f2bf(s[j]);
}

// ---------------- combineF: out = relu(sum_s P[s] (bf16)) -> f32 [4][8192][64] ------------
__global__ __launch_bounds__(256) void combineF(const uint16_t* __restrict__ P,
                                                float* __restrict__ out) {
  const uint64_t e = ((uint64_t)blockIdx.x * 256 + threadIdx.x) * 8;
  float acc8[8] = {};
#pragma unroll
  for (int sp = 0; sp < 8; ++sp) {
    u32x4 v = *(const u32x4*)&P[(uint64_t)sp * 2097152 + e];
#pragma unroll
    for (int j = 0; j < 4; ++j) {
      acc8[2 * j]     += bf2f(v[j] & 0xffffu);
      acc8[2 * j + 1] += bf2f(v[j] >> 16);
    }
  }
  const int m = (int)(e >> 8);
  const int c = (int)(e & 255);
  float* dst = &out[(((uint64_t)(c >> 6)) * MK + m) * 64 + (c & 63)];
  f32x4 w0, w1;
#pragma unroll
  for (int j = 0; j < 4; ++j) { w0[j] = fmaxf(acc8[j], 0.0f); w1[j] = fmaxf(acc8[4 + j], 0.0f); }
  *(f32x4*)dst = w0;
  *(f32x4*)(dst + 4) = w1;
}

extern "C" void kernel_launch(void* const* d_in, const int* in_sizes, int n_in,
                              void* d_out, int out_size, void* d_ws, size_t ws_size,
                              hipStream_t stream) {
  const float* x   = (const float*)d_in[0];
  const float* net = (const float*)d_in[2];
  const float* A   = (const float*)d_in[3];
  float* out = (float*)d_out;

  uint16_t* Ab = (uint16_t*)d_ws;                               // 128 MiB
  uint16_t* Zt = (uint16_t*)((char*)d_ws + 134217728ull);       // 4 MiB
  uint16_t* P  = (uint16_t*)((char*)d_ws + 142606336ull);       // 32 MiB (bf16 [8][8192][256])

  zw0<<<dim3(128, 4), dim3(256), 0, stream>>>(x, net, Zt);
  gemm1<<<dim3(256), dim3(512), 0, stream>>>(A, Zt, Ab, P);
  zw1P<<<dim3(128, 4), dim3(256), 0, stream>>>(P, net, Zt);
  gemm2<<<dim3(256), dim3(512), 0, stream>>>(Ab, Zt, P);
  combineF<<<dim3(1024), dim3(256), 0, stream>>>(P, out);
}